// Round 15
// baseline (226.993 us; speedup 1.0000x reference)
//
#include <hip/hip_runtime.h>
#include <math.h>

#define BSZ 2
#define LSEQ 1024
#define DM 1024
#define DI 2048
#define DS 16
#define MROWS (BSZ * LSEQ)   // 2048
#define NC 64                // time chunks for parallel scan
#define CLEN (LSEQ / NC)     // 16
#define BK 64                // GEMM K-step (64 halfwords = 128B/row)
#define NDT 2176             // dt GEMM N: 2048 delta + 32 bc + 96 pad

typedef __attribute__((ext_vector_type(8))) _Float16 half8;
typedef __attribute__((ext_vector_type(4))) float f32x4;

// async global->LDS, 16 bytes per lane; lds base must be wave-uniform
__device__ inline void gload16(const void* g, void* l) {
  __builtin_amdgcn_global_load_lds(
      (const __attribute__((address_space(1))) unsigned*)g,
      (__attribute__((address_space(3))) unsigned*)l, 16, 0, 0);
}

__device__ inline float softplus_f(float t) {
  return (t > 20.f) ? t : log1pf(expf(t));
}

// ---------- merged prep: fp32 -> fp16 convert ----------
__device__ inline void cvt8_at(const float* __restrict__ in, _Float16* __restrict__ o,
                               int i) {
  f32x4 a = *(const f32x4*)(in + i);
  f32x4 b = *(const f32x4*)(in + i + 4);
  half8 h;
#pragma unroll
  for (int j = 0; j < 4; ++j) h[j] = (_Float16)a[j];
#pragma unroll
  for (int j = 0; j < 4; ++j) h[4 + j] = (_Float16)b[j];
  *(half8*)(o + i) = h;
}

// dt weight buffer layout: rows 0..2047 = dt_proj_w, 2048..2079 = x_proj_w,
// 2080..2175 = zeros (padding to a 128-multiple of N)
__global__ void prep(const float* __restrict__ x, const float* __restrict__ wi,
                     const float* __restrict__ wdt, const float* __restrict__ xp,
                     const float* __restrict__ wo,
                     _Float16* __restrict__ xh, _Float16* __restrict__ wih,
                     _Float16* __restrict__ dtwp, _Float16* __restrict__ oh) {
  int blk = blockIdx.x, tid = threadIdx.x;
  if (blk < 1024) {                       // x: 2M elems
    cvt8_at(x, xh, (blk * 256 + tid) * 8);
  } else if (blk < 3072) {                // in_proj_w: 4M
    cvt8_at(wi, wih, ((blk - 1024) * 256 + tid) * 8);
  } else if (blk < 5120) {                // dt_proj_w: 4M
    cvt8_at(wdt, dtwp, ((blk - 3072) * 256 + tid) * 8);
  } else if (blk < 5152) {                // x_proj_w: 64K
    cvt8_at(xp, dtwp + (size_t)DI * DI, ((blk - 5120) * 256 + tid) * 8);
  } else if (blk < 5248) {                // zero pad rows
    int i = ((blk - 5152) * 256 + tid) * 8;
    *(half8*)(dtwp + (size_t)(DI + 32) * DI + i) = (half8){0, 0, 0, 0, 0, 0, 0, 0};
  } else {                                // out_proj_w: 2M
    cvt8_at(wo, oh, ((blk - 5248) * 256 + tid) * 8);
  }
}

// ---------- fp16 MFMA GEMM: C[M,N] = A[M,K] * W[N,K]^T ----------
// BK=64, XOR-swizzled LDS, TRIPLE-buffered: 2 stages stay in flight across
// the single per-iter barrier; counted vmcnt(2*PF / PF / 0).
// TM=64, TN=128 fixed (PF = 2 + 4 = 6 loads/thread/stage).
// OT: 0 = fp32 store (z-sliced partial), 1 = fp16 store,
//     3 = dt fused epilogue: n<DI -> softplus fp16 (stride ldc), else bc fp32
template <int TM, int TN, int OT>
__global__ __launch_bounds__(256) void gemm_mfma(
    const _Float16* __restrict__ Ag, const _Float16* __restrict__ Whg,
    const float* __restrict__ bias, void* __restrict__ Cv,
    float* __restrict__ C2, int M, int N, int K, int ldc) {
  constexpr int FI = TM / 32, FJ = TN / 32;
  __shared__ _Float16 Ab[3][TM * BK], Wb[3][TN * BK];
  int tid = threadIdx.x, lane = tid & 63, wid = tid >> 6;

  // split-K slice
  int ksl = K / gridDim.z;
  int kBeg = blockIdx.z * ksl;
  int NI = ksl / BK;

  // XCD-aware swizzle (nwg is a multiple of 8 for all our launches)
  int gx = gridDim.x, nwg = gx * gridDim.y;
  int id = blockIdx.y * gx + blockIdx.x;
  int swz = (id & 7) * (nwg >> 3) + (id >> 3);
  int m0 = (swz / gx) * TM, n0 = (swz % gx) * TN;

  int wm = (wid >> 1) * (TM / 2), wn = (wid & 1) * (TN / 2);
  int fr = lane & 15, fq = lane >> 4;

  // staging: LDS[row][slot] = G[row][slot ^ (row&7)], slot = 16B unit
  auto stage = [&](int buf, int k0) {
#pragma unroll
    for (int q = 0; q < TM / 32; ++q) {
      int i = q * 256 + tid;
      int row = i >> 3, slot = i & 7;
      size_t go = (size_t)(m0 + row) * K + k0 + ((slot ^ (row & 7)) * 8);
      gload16(Ag + go, &Ab[buf][(q * 256 + wid * 64) * 8]);
    }
#pragma unroll
    for (int q = 0; q < TN / 32; ++q) {
      int i = q * 256 + tid;
      int row = i >> 3, slot = i & 7;
      size_t go = (size_t)(n0 + row) * K + k0 + ((slot ^ (row & 7)) * 8);
      gload16(Whg + go, &Wb[buf][(q * 256 + wid * 64) * 8]);
    }
  };

  f32x4 acc[FI][FJ];
#pragma unroll
  for (int i = 0; i < FI; ++i)
#pragma unroll
    for (int j = 0; j < FJ; ++j) acc[i][j] = (f32x4){0.f, 0.f, 0.f, 0.f};

  stage(0, kBeg);
  stage(1, kBeg + BK);
  int cur = 0;
  for (int it = 0; it < NI; ++it) {
    // barrier: all waves done reading the buffer the next stage overwrites
    __builtin_amdgcn_s_barrier();
    if (it + 2 < NI) stage((cur + 2) % 3, kBeg + (it + 2) * BK);
    int rem = NI - 1 - it;
    if (rem >= 2)      asm volatile("s_waitcnt vmcnt(12)" ::: "memory");
    else if (rem == 1) asm volatile("s_waitcnt vmcnt(6)" ::: "memory");
    else               asm volatile("s_waitcnt vmcnt(0)" ::: "memory");
    __builtin_amdgcn_sched_barrier(0);     // pin ds_reads below the wait

    half8 a[FI][2], w[FJ][2];
#pragma unroll
    for (int f = 0; f < FI; ++f) {
      int row = wm + f * 16 + fr;
#pragma unroll
      for (int kk = 0; kk < 2; ++kk)
        a[f][kk] = *(const half8*)&Ab[cur][row * BK + (((kk * 4 + fq) ^ (row & 7)) * 8)];
    }
#pragma unroll
    for (int f = 0; f < FJ; ++f) {
      int row = wn + f * 16 + fr;
#pragma unroll
      for (int kk = 0; kk < 2; ++kk)
        w[f][kk] = *(const half8*)&Wb[cur][row * BK + (((kk * 4 + fq) ^ (row & 7)) * 8)];
    }
#pragma unroll
    for (int kk = 0; kk < 2; ++kk)
#pragma unroll
      for (int i = 0; i < FI; ++i)
#pragma unroll
        for (int j = 0; j < FJ; ++j)
          acc[i][j] = __builtin_amdgcn_mfma_f32_16x16x32_f16(a[i][kk], w[j][kk], acc[i][j], 0, 0, 0);

    __builtin_amdgcn_sched_barrier(0);     // keep this iter's ds_reads here
    cur = (cur + 1) % 3;
  }

#pragma unroll
  for (int i = 0; i < FI; ++i) {
    int m = m0 + wm + i * 16 + fq * 4;
#pragma unroll
    for (int j = 0; j < FJ; ++j) {
      int n = n0 + wn + j * 16 + fr;
#pragma unroll
      for (int r = 0; r < 4; ++r) {
        float v = acc[i][j][r];
        if constexpr (OT == 0) {
          ((float*)Cv)[(size_t)blockIdx.z * M * ldc + (size_t)(m + r) * ldc + n] = v;
        } else if constexpr (OT == 1) {
          ((_Float16*)Cv)[(size_t)(m + r) * ldc + n] = (_Float16)v;
        } else {
          if (n < DI)
            ((_Float16*)Cv)[(size_t)(m + r) * ldc + n] =
                (_Float16)softplus_f(v + bias[n]);
          else if (n < DI + 32)
            C2[(size_t)(m + r) * 32 + (n - DI)] = v;
        }
      }
    }
  }
}

// ---------- split-K reduction (plain add, for out_proj) ----------
__global__ void reduce2(const float* __restrict__ P, float* __restrict__ C, int MN) {
  int i = (blockIdx.x * 256 + threadIdx.x) * 4;
  f32x4 a = *(const f32x4*)(P + i);
  f32x4 b = *(const f32x4*)(P + MN + i);
  *(f32x4*)(C + i) = a + b;
}

// ---------- depthwise conv1d k=3 pad=1 + bias + silu -> fp16 (fp16 in) ----------
__global__ void conv_silu(const _Float16* __restrict__ xzh, const float* __restrict__ cw,
                          const float* __restrict__ cb,
                          _Float16* __restrict__ xsch) {
  int idx = blockIdx.x * 256 + threadIdx.x;  // over B*L*DI
  int d = idx & (DI - 1);
  int bt = idx >> 11;           // row index (b*L + t)
  int t = bt & (LSEQ - 1);
  const _Float16* base = xzh + (size_t)bt * (2 * DI) + d;  // xs part
  float acc = cb[d];
  float w0 = cw[d * 3 + 0], w1 = cw[d * 3 + 1], w2 = cw[d * 3 + 2];
  if (t > 0) acc += (float)base[-(2 * DI)] * w0;
  acc += (float)base[0] * w1;
  if (t < LSEQ - 1) acc += (float)base[2 * DI] * w2;
  float s = acc / (1.f + __expf(-acc));   // silu
  xsch[idx] = (_Float16)s;
}

// ---------- chunked parallel scan ----------
// Phase A: per (b,d,chunk): local scan h0=0 (delta precomputed fp16).
__global__ void scan_phaseA(const _Float16* __restrict__ dlth,
                            const _Float16* __restrict__ xsch,
                            const float* __restrict__ bc,
                            const float* __restrict__ A_log,
                            float* __restrict__ hloc,
                            float* __restrict__ dsum) {
  int tid = threadIdx.x;
  int d = blockIdx.x * 256 + tid;
  int c = blockIdx.y;
  int b = blockIdx.z;
  float Av[DS];
#pragma unroll
  for (int n = 0; n < DS; n += 4) {
    float4 v = *(const float4*)(A_log + d * DS + n);
    Av[n] = -__expf(v.x); Av[n+1] = -__expf(v.y);
    Av[n+2] = -__expf(v.z); Av[n+3] = -__expf(v.w);
  }
  float h[DS] = {};
  float sd = 0.f;
  size_t row = (size_t)b * LSEQ + (size_t)c * CLEN;
  for (int t = 0; t < CLEN; ++t, ++row) {
    float dlt = (float)dlth[row * DI + d];
    float xv  = (float)xsch[row * DI + d];
    float dx = dlt * xv;
    sd += dlt;
#pragma unroll
    for (int n = 0; n < DS; ++n) {
      float Bn = bc[row * 32 + n];
      float dA = __expf(dlt * Av[n]);
      h[n] = dA * h[n] + dx * Bn;
    }
  }
  size_t o = ((size_t)(b * NC + c) * DI + d) * DS;
#pragma unroll
  for (int n = 0; n < DS; n += 4)
    *(float4*)(hloc + o + n) = make_float4(h[n], h[n+1], h[n+2], h[n+3]);
  dsum[(b * NC + c) * DI + d] = sd;
}

// Phase B: wave-segmented affine scan over chunks. One wave per (b,d);
// lane = (seg, n): seg in [0,4) handles 16 chunks; 2-step shuffle compose.
__global__ void scan_phaseB(const float* __restrict__ hloc,
                            const float* __restrict__ dsum,
                            const float* __restrict__ A_log,
                            float* __restrict__ hin) {
  int tid = threadIdx.x, lane = tid & 63, wid = tid >> 6;
  int n = lane & 15, seg = lane >> 4;
  int dg = blockIdx.x * 4 + wid;          // over B*DI
  int b = dg >> 11, d = dg & (DI - 1);
  float Av = -__expf(A_log[d * DS + n]);
  float p[CLEN], q[CLEN];
  float P = 1.f, Q = 0.f;
  int c0 = seg * 16;
#pragma unroll
  for (int i = 0; i < 16; ++i) {
    size_t cb = (size_t)(b * NC + c0 + i) * DI + d;
    float pi = __expf(Av * dsum[cb]);
    float qi = hloc[cb * DS + n];
    p[i] = pi; q[i] = qi;
    Q = pi * Q + qi;
    P *= pi;
  }
  // Hillis-Steele inclusive scan across the 4 segments (affine compose)
#pragma unroll
  for (int off = 16; off <= 32; off <<= 1) {
    float Pp = __shfl_up(P, off, 64);
    float Qp = __shfl_up(Q, off, 64);
    if (lane >= off) { Q = P * Qp + Q; P = P * Pp; }
  }
  float h = __shfl_up(Q, 16, 64);   // exclusive prefix (h0 = 0)
  if (seg == 0) h = 0.f;
#pragma unroll
  for (int i = 0; i < 16; ++i) {
    size_t cb = (size_t)(b * NC + c0 + i) * DI + d;
    hin[cb * DS + n] = h;
    h = p[i] * h + q[i];
  }
}

// Phase C: scan within chunk seeded with hin; hidden written coalesced via
// double-buffered LDS (1 barrier/iter) + nontemporal stores;
// fused y = (sum h*C + x*D) * silu(z) emitted as fp16 for the out_proj GEMM.
#define HS_STRIDE 20   // floats; 80B: 16B-aligned, breaks 64B bank pattern
__global__ void scan_phaseC(const _Float16* __restrict__ dlth,
                            const _Float16* __restrict__ xsch,
                            const float* __restrict__ bc,
                            const _Float16* __restrict__ xzh,
                            const float* __restrict__ A_log,
                            const float* __restrict__ Dv,
                            const float* __restrict__ hin,
                            float* __restrict__ hidden,
                            _Float16* __restrict__ yh) {
  __shared__ float hs[2][256 * HS_STRIDE];
  int tid = threadIdx.x;
  int d0 = blockIdx.x * 256;
  int d = d0 + tid;
  int c = blockIdx.y;
  int b = blockIdx.z;
  float Av[DS];
#pragma unroll
  for (int n = 0; n < DS; n += 4) {
    float4 v = *(const float4*)(A_log + d * DS + n);
    Av[n] = -__expf(v.x); Av[n+1] = -__expf(v.y);
    Av[n+2] = -__expf(v.z); Av[n+3] = -__expf(v.w);
  }
  float Dd = Dv[d];
  float h[DS];
  size_t so = ((size_t)(b * NC + c) * DI + d) * DS;
#pragma unroll
  for (int n = 0; n < DS; n += 4) {
    float4 v = *(const float4*)(hin + so + n);
    h[n] = v.x; h[n+1] = v.y; h[n+2] = v.z; h[n+3] = v.w;
  }
  size_t row = (size_t)b * LSEQ + (size_t)c * CLEN;
  for (int t = 0; t < CLEN; ++t, ++row) {
    int bufi = t & 1;
    float dlt = (float)dlth[row * DI + d];
    float xv  = (float)xsch[row * DI + d];
    float dx = dlt * xv;
    float y = 0.f;
#pragma unroll
    for (int n = 0; n < DS; ++n) {
      float Bn = bc[row * 32 + n];
      float Cn = bc[row * 32 + 16 + n];
      float dA = __expf(dlt * Av[n]);
      h[n] = dA * h[n] + dx * Bn;
      y += h[n] * Cn;
    }
    // stage h into LDS, then cooperatively write 16KB contiguous (nontemporal)
#pragma unroll
    for (int n = 0; n < DS; n += 4)
      *(f32x4*)&hs[bufi][tid * HS_STRIDE + n] = (f32x4){h[n], h[n+1], h[n+2], h[n+3]};
    __syncthreads();
    size_t basef = ((size_t)row * DI + d0) * DS;   // 4096 floats for this block
#pragma unroll
    for (int k = 0; k < 4; ++k) {
      int f4 = tid + 256 * k;            // float4 index within slab
      int owner = f4 >> 2;
      int elem = (f4 & 3) * 4;
      f32x4 v = *(const f32x4*)&hs[bufi][owner * HS_STRIDE + elem];
      __builtin_nontemporal_store(v, (f32x4*)&hidden[basef + (size_t)f4 * 4]);
    }
    float zv = (float)xzh[row * (2 * DI) + DI + d];
    float sz = zv / (1.f + __expf(-zv));
    yh[row * DI + d] = (_Float16)((y + xv * Dd) * sz);
  }
}

extern "C" void kernel_launch(void* const* d_in, const int* in_sizes, int n_in,
                              void* d_out, int out_size, void* d_ws, size_t ws_size,
                              hipStream_t stream) {
  const float* x         = (const float*)d_in[0];
  const float* in_proj_w = (const float*)d_in[1];
  const float* conv_w    = (const float*)d_in[2];
  const float* conv_b    = (const float*)d_in[3];
  const float* x_proj_w  = (const float*)d_in[4];
  const float* dt_proj_w = (const float*)d_in[5];
  const float* dt_proj_b = (const float*)d_in[6];
  const float* out_proj_w= (const float*)d_in[7];
  const float* A_log     = (const float*)d_in[8];
  const float* Dvec      = (const float*)d_in[9];

  float* out    = (float*)d_out;                            // (B,L,DM)
  float* hidden = (float*)d_out + (size_t)BSZ * LSEQ * DM;  // (B,L,DI,DS)

  float* ws  = (float*)d_ws;
  float* bcbuf = ws;                                   // (M, 32)
  float* hloc  = bcbuf + (size_t)MROWS * 32;           // (B,NC,DI,DS) 4M
  float* hin   = hloc + (size_t)BSZ * NC * DI * DS;    // (B,NC,DI,DS) 4M
  float* dsum  = hin  + (size_t)BSZ * NC * DI * DS;    // (B,NC,DI)  256K
  float* outP  = dsum + (size_t)BSZ * NC * DI;         // 2x(M,DM)   4M

  _Float16* hp = (_Float16*)(outP + (size_t)2 * MROWS * DM);
  _Float16* xh   = hp;                                 // (M,DM)     2M
  _Float16* wih  = xh + (size_t)MROWS * DM;            // (2DI,DM)   4M
  _Float16* dtwp = wih + (size_t)2 * DI * DM;          // (NDT,DI)   4.45M
  _Float16* oh   = dtwp + (size_t)NDT * DI;            // (DM,DI)    2M
  _Float16* xzh  = oh + (size_t)DM * DI;               // (M,2DI)    8M
  _Float16* dlth = xzh + (size_t)MROWS * 2 * DI;       // (M,DI)     4M
  _Float16* xsch = dlth + (size_t)MROWS * DI;          // (M,DI)     4M
  _Float16* yh   = xsch + (size_t)MROWS * DI;          // (M,DI)     4M

  dim3 blk(256);

  // 0) merged prep: cvt x + all weight matrices to fp16 (+ dt/bc fusion pad)
  prep<<<dim3(6272), blk, 0, stream>>>(x, in_proj_w, dt_proj_w, x_proj_w,
                                       out_proj_w, xh, wih, dtwp, oh);

  // 1) xz = x @ in_proj_w^T -> fp16  (M=2048, N=4096, K=1024); 1024 blocks
  gemm_mfma<64, 128, 1><<<dim3((2 * DI) / 128, MROWS / 64), blk, 0, stream>>>(
      xh, wih, nullptr, xzh, nullptr, MROWS, 2 * DI, DM, 2 * DI);

  // 2) depthwise conv + silu -> xsch (fp16)
  conv_silu<<<dim3((BSZ * LSEQ * DI) / 256), blk, 0, stream>>>(
      xzh, conv_w, conv_b, xsch);

  // 3) fused dt+bc GEMM (544 blocks)
  gemm_mfma<64, 128, 3><<<dim3(NDT / 128, MROWS / 64), blk, 0, stream>>>(
      xsch, dtwp, dt_proj_b, dlth, bcbuf, MROWS, NDT, DI, DI);

  // 4) chunked parallel scan -> hidden, y (fp16)
  scan_phaseA<<<dim3(DI / 256, NC, BSZ), blk, 0, stream>>>(
      dlth, xsch, bcbuf, A_log, hloc, dsum);
  scan_phaseB<<<dim3((BSZ * DI) / 4), blk, 0, stream>>>(
      hloc, dsum, A_log, hin);
  scan_phaseC<<<dim3(DI / 256, NC, BSZ), blk, 0, stream>>>(
      dlth, xsch, bcbuf, xzh, A_log, Dvec, hin, hidden, yh);

  // 5) out partials (split-K=2; 512 blocks), then out = P0+P1
  gemm_mfma<64, 128, 0><<<dim3(DM / 128, MROWS / 64, 2), blk, 0, stream>>>(
      yh, oh, nullptr, outP, nullptr, MROWS, DM, DI, DM);
  reduce2<<<dim3((MROWS * DM) / 1024), blk, 0, stream>>>(
      outP, out, MROWS * DM);
}

// Round 16
// 200.985 us; speedup vs baseline: 1.1294x; 1.1294x over previous
//
#include <hip/hip_runtime.h>
#include <math.h>

#define BSZ 2
#define LSEQ 1024
#define DM 1024
#define DI 2048
#define DS 16
#define MROWS (BSZ * LSEQ)   // 2048
#define NC 64                // time chunks for parallel scan
#define CLEN (LSEQ / NC)     // 16
#define BK 64                // GEMM K-step (64 halfwords = 128B/row)
#define NDT 2176             // dt GEMM N: 2048 delta + 32 bc + 96 pad

typedef __attribute__((ext_vector_type(8))) _Float16 half8;
typedef __attribute__((ext_vector_type(4))) float f32x4;

// async global->LDS, 16 bytes per lane; lds base must be wave-uniform
__device__ inline void gload16(const void* g, void* l) {
  __builtin_amdgcn_global_load_lds(
      (const __attribute__((address_space(1))) unsigned*)g,
      (__attribute__((address_space(3))) unsigned*)l, 16, 0, 0);
}

__device__ inline float softplus_f(float t) {
  return (t > 20.f) ? t : log1pf(expf(t));
}

// ---------- merged prep: fp32 -> fp16 convert ----------
__device__ inline void cvt8_at(const float* __restrict__ in, _Float16* __restrict__ o,
                               int i) {
  f32x4 a = *(const f32x4*)(in + i);
  f32x4 b = *(const f32x4*)(in + i + 4);
  half8 h;
#pragma unroll
  for (int j = 0; j < 4; ++j) h[j] = (_Float16)a[j];
#pragma unroll
  for (int j = 0; j < 4; ++j) h[4 + j] = (_Float16)b[j];
  *(half8*)(o + i) = h;
}

// dt weight buffer layout: rows 0..2047 = dt_proj_w, 2048..2079 = x_proj_w,
// 2080..2175 = zeros (padding to a 128-multiple of N)
__global__ void prep(const float* __restrict__ x, const float* __restrict__ wi,
                     const float* __restrict__ wdt, const float* __restrict__ xp,
                     const float* __restrict__ wo,
                     _Float16* __restrict__ xh, _Float16* __restrict__ wih,
                     _Float16* __restrict__ dtwp, _Float16* __restrict__ oh) {
  int blk = blockIdx.x, tid = threadIdx.x;
  if (blk < 1024) {                       // x: 2M elems
    cvt8_at(x, xh, (blk * 256 + tid) * 8);
  } else if (blk < 3072) {                // in_proj_w: 4M
    cvt8_at(wi, wih, ((blk - 1024) * 256 + tid) * 8);
  } else if (blk < 5120) {                // dt_proj_w: 4M
    cvt8_at(wdt, dtwp, ((blk - 3072) * 256 + tid) * 8);
  } else if (blk < 5152) {                // x_proj_w: 64K
    cvt8_at(xp, dtwp + (size_t)DI * DI, ((blk - 5120) * 256 + tid) * 8);
  } else if (blk < 5248) {                // zero pad rows
    int i = ((blk - 5152) * 256 + tid) * 8;
    *(half8*)(dtwp + (size_t)(DI + 32) * DI + i) = (half8){0, 0, 0, 0, 0, 0, 0, 0};
  } else {                                // out_proj_w: 2M
    cvt8_at(wo, oh, ((blk - 5248) * 256 + tid) * 8);
  }
}

// ---------- fp16 MFMA GEMM: C[M,N] = A[M,K] * W[N,K]^T ----------
// BK=64, XOR-swizzled LDS, double-buffer w/ counted vmcnt + raw barriers.
// Split-K via gridDim.z (fp32 partials stacked for OT==0).
// OT: 0 = fp32 store (z-sliced partial), 1 = fp16 store,
//     3 = dt fused epilogue: n<DI -> softplus fp16 (stride ldc), else bc fp32
template <int TM, int TN, int OT>
__global__ __launch_bounds__(256) void gemm_mfma(
    const _Float16* __restrict__ Ag, const _Float16* __restrict__ Whg,
    const float* __restrict__ bias, void* __restrict__ Cv,
    float* __restrict__ C2, int M, int N, int K, int ldc) {
  constexpr int FI = TM / 32, FJ = TN / 32;
  constexpr int PF = TM / 32 + TN / 32;   // loads per thread per stage
  __shared__ _Float16 Ab[2][TM * BK], Wb[2][TN * BK];
  int tid = threadIdx.x, lane = tid & 63, wid = tid >> 6;

  // split-K slice
  int ksl = K / gridDim.z;
  int kBeg = blockIdx.z * ksl, kEnd = kBeg + ksl;

  // XCD-aware swizzle (nwg is a multiple of 8 for all our launches)
  int gx = gridDim.x, nwg = gx * gridDim.y;
  int id = blockIdx.y * gx + blockIdx.x;
  int swz = (id & 7) * (nwg >> 3) + (id >> 3);
  int m0 = (swz / gx) * TM, n0 = (swz % gx) * TN;

  int wm = (wid >> 1) * (TM / 2), wn = (wid & 1) * (TN / 2);
  int fr = lane & 15, fq = lane >> 4;

  // staging: LDS[row][slot] = G[row][slot ^ (row&7)], slot = 16B unit
  auto stage = [&](int buf, int k0) {
#pragma unroll
    for (int q = 0; q < TM / 32; ++q) {
      int i = q * 256 + tid;
      int row = i >> 3, slot = i & 7;
      size_t go = (size_t)(m0 + row) * K + k0 + ((slot ^ (row & 7)) * 8);
      gload16(Ag + go, &Ab[buf][(q * 256 + wid * 64) * 8]);
    }
#pragma unroll
    for (int q = 0; q < TN / 32; ++q) {
      int i = q * 256 + tid;
      int row = i >> 3, slot = i & 7;
      size_t go = (size_t)(n0 + row) * K + k0 + ((slot ^ (row & 7)) * 8);
      gload16(Whg + go, &Wb[buf][(q * 256 + wid * 64) * 8]);
    }
  };

  f32x4 acc[FI][FJ];
#pragma unroll
  for (int i = 0; i < FI; ++i)
#pragma unroll
    for (int j = 0; j < FJ; ++j) acc[i][j] = (f32x4){0.f, 0.f, 0.f, 0.f};

  stage(0, kBeg);             // prologue: buf0 loads in flight
  int cur = 0;
  for (int k0 = kBeg; k0 < kEnd; k0 += BK) {
    if (k0 + BK < kEnd) {
      stage(cur ^ 1, k0 + BK);   // prefetch next tile (stays in flight)
      if constexpr (PF == 8)
        asm volatile("s_waitcnt vmcnt(8)" ::: "memory");
      else
        asm volatile("s_waitcnt vmcnt(6)" ::: "memory");
    } else {
      asm volatile("s_waitcnt vmcnt(0)" ::: "memory");
    }
    __builtin_amdgcn_s_barrier();          // raw: no auto vmcnt(0) drain
    __builtin_amdgcn_sched_barrier(0);     // pin ds_reads below the barrier

    half8 a[FI][2], w[FJ][2];
#pragma unroll
    for (int f = 0; f < FI; ++f) {
      int row = wm + f * 16 + fr;
#pragma unroll
      for (int kk = 0; kk < 2; ++kk)
        a[f][kk] = *(const half8*)&Ab[cur][row * BK + (((kk * 4 + fq) ^ (row & 7)) * 8)];
    }
#pragma unroll
    for (int f = 0; f < FJ; ++f) {
      int row = wn + f * 16 + fr;
#pragma unroll
      for (int kk = 0; kk < 2; ++kk)
        w[f][kk] = *(const half8*)&Wb[cur][row * BK + (((kk * 4 + fq) ^ (row & 7)) * 8)];
    }
#pragma unroll
    for (int kk = 0; kk < 2; ++kk)
#pragma unroll
      for (int i = 0; i < FI; ++i)
#pragma unroll
        for (int j = 0; j < FJ; ++j)
          acc[i][j] = __builtin_amdgcn_mfma_f32_16x16x32_f16(a[i][kk], w[j][kk], acc[i][j], 0, 0, 0);

    __builtin_amdgcn_sched_barrier(0);     // keep ds_reads above barrier-2
    __builtin_amdgcn_s_barrier();          // all waves done reading buf cur
    cur ^= 1;
  }

#pragma unroll
  for (int i = 0; i < FI; ++i) {
    int m = m0 + wm + i * 16 + fq * 4;
#pragma unroll
    for (int j = 0; j < FJ; ++j) {
      int n = n0 + wn + j * 16 + fr;
#pragma unroll
      for (int r = 0; r < 4; ++r) {
        float v = acc[i][j][r];
        if constexpr (OT == 0) {
          ((float*)Cv)[(size_t)blockIdx.z * M * ldc + (size_t)(m + r) * ldc + n] = v;
        } else if constexpr (OT == 1) {
          ((_Float16*)Cv)[(size_t)(m + r) * ldc + n] = (_Float16)v;
        } else {
          if (n < DI)
            ((_Float16*)Cv)[(size_t)(m + r) * ldc + n] =
                (_Float16)softplus_f(v + bias[n]);
          else if (n < DI + 32)
            C2[(size_t)(m + r) * 32 + (n - DI)] = v;
        }
      }
    }
  }
}

// ---------- split-K reduction (plain add, for out_proj) ----------
__global__ void reduce2(const float* __restrict__ P, float* __restrict__ C, int MN) {
  int i = (blockIdx.x * 256 + threadIdx.x) * 4;
  f32x4 a = *(const f32x4*)(P + i);
  f32x4 b = *(const f32x4*)(P + MN + i);
  *(f32x4*)(C + i) = a + b;
}

// ---------- depthwise conv1d k=3 pad=1 + bias + silu -> fp16 (vectorized) ----------
// 8 channels per thread: half8 loads of rows t-1/t/t+1, f32x4 weight loads.
__global__ void conv_silu(const _Float16* __restrict__ xzh, const float* __restrict__ cw,
                          const float* __restrict__ cb,
                          _Float16* __restrict__ xsch) {
  int idx = blockIdx.x * 256 + threadIdx.x;  // over B*L*(DI/8)
  int d8 = (idx & (DI / 8 - 1)) * 8;
  int bt = idx >> 8;            // row index (b*L + t)
  int t = bt & (LSEQ - 1);
  const _Float16* base = xzh + (size_t)bt * (2 * DI) + d8;  // xs part
  half8 prev = (t > 0) ? *(const half8*)(base - 2 * DI)
                       : (half8){0, 0, 0, 0, 0, 0, 0, 0};
  half8 curv = *(const half8*)base;
  half8 nxt = (t < LSEQ - 1) ? *(const half8*)(base + 2 * DI)
                             : (half8){0, 0, 0, 0, 0, 0, 0, 0};
  // weights: cw[d*3 + k]; 24 consecutive floats for 8 channels
  float wv[24];
#pragma unroll
  for (int q = 0; q < 6; ++q)
    *(f32x4*)&wv[q * 4] = *(const f32x4*)(cw + d8 * 3 + q * 4);
  f32x4 b0 = *(const f32x4*)(cb + d8);
  f32x4 b1 = *(const f32x4*)(cb + d8 + 4);
  half8 o;
#pragma unroll
  for (int j = 0; j < 8; ++j) {
    float acc = (j < 4) ? b0[j] : b1[j - 4];
    acc += (float)prev[j] * wv[j * 3 + 0];
    acc += (float)curv[j] * wv[j * 3 + 1];
    acc += (float)nxt[j]  * wv[j * 3 + 2];
    float s = acc / (1.f + __expf(-acc));   // silu
    o[j] = (_Float16)s;
  }
  *(half8*)(xsch + (size_t)bt * DI + d8) = o;
}

// ---------- chunked parallel scan ----------
// Phase A: per (b,d,chunk): local scan h0=0 (delta precomputed fp16).
__global__ void scan_phaseA(const _Float16* __restrict__ dlth,
                            const _Float16* __restrict__ xsch,
                            const float* __restrict__ bc,
                            const float* __restrict__ A_log,
                            float* __restrict__ hloc,
                            float* __restrict__ dsum) {
  int tid = threadIdx.x;
  int d = blockIdx.x * 256 + tid;
  int c = blockIdx.y;
  int b = blockIdx.z;
  float Av[DS];
#pragma unroll
  for (int n = 0; n < DS; n += 4) {
    float4 v = *(const float4*)(A_log + d * DS + n);
    Av[n] = -__expf(v.x); Av[n+1] = -__expf(v.y);
    Av[n+2] = -__expf(v.z); Av[n+3] = -__expf(v.w);
  }
  float h[DS] = {};
  float sd = 0.f;
  size_t row = (size_t)b * LSEQ + (size_t)c * CLEN;
  for (int t = 0; t < CLEN; ++t, ++row) {
    float dlt = (float)dlth[row * DI + d];
    float xv  = (float)xsch[row * DI + d];
    float dx = dlt * xv;
    sd += dlt;
#pragma unroll
    for (int n = 0; n < DS; ++n) {
      float Bn = bc[row * 32 + n];
      float dA = __expf(dlt * Av[n]);
      h[n] = dA * h[n] + dx * Bn;
    }
  }
  size_t o = ((size_t)(b * NC + c) * DI + d) * DS;
#pragma unroll
  for (int n = 0; n < DS; n += 4)
    *(float4*)(hloc + o + n) = make_float4(h[n], h[n+1], h[n+2], h[n+3]);
  dsum[(b * NC + c) * DI + d] = sd;
}

// Phase B: wave-segmented affine scan over chunks. One wave per (b,d);
// lane = (seg, n): seg in [0,4) handles 16 chunks; 2-step shuffle compose.
__global__ void scan_phaseB(const float* __restrict__ hloc,
                            const float* __restrict__ dsum,
                            const float* __restrict__ A_log,
                            float* __restrict__ hin) {
  int tid = threadIdx.x, lane = tid & 63, wid = tid >> 6;
  int n = lane & 15, seg = lane >> 4;
  int dg = blockIdx.x * 4 + wid;          // over B*DI
  int b = dg >> 11, d = dg & (DI - 1);
  float Av = -__expf(A_log[d * DS + n]);
  float p[CLEN], q[CLEN];
  float P = 1.f, Q = 0.f;
  int c0 = seg * 16;
#pragma unroll
  for (int i = 0; i < 16; ++i) {
    size_t cb = (size_t)(b * NC + c0 + i) * DI + d;
    float pi = __expf(Av * dsum[cb]);
    float qi = hloc[cb * DS + n];
    p[i] = pi; q[i] = qi;
    Q = pi * Q + qi;
    P *= pi;
  }
  // Hillis-Steele inclusive scan across the 4 segments (affine compose)
#pragma unroll
  for (int off = 16; off <= 32; off <<= 1) {
    float Pp = __shfl_up(P, off, 64);
    float Qp = __shfl_up(Q, off, 64);
    if (lane >= off) { Q = P * Qp + Q; P = P * Pp; }
  }
  float h = __shfl_up(Q, 16, 64);   // exclusive prefix (h0 = 0)
  if (seg == 0) h = 0.f;
#pragma unroll
  for (int i = 0; i < 16; ++i) {
    size_t cb = (size_t)(b * NC + c0 + i) * DI + d;
    hin[cb * DS + n] = h;
    h = p[i] * h + q[i];
  }
}

// Phase C: scan within chunk seeded with hin; hidden written coalesced via
// double-buffered LDS (1 barrier/iter) + nontemporal stores;
// fused y = (sum h*C + x*D) * silu(z) emitted as fp16 for the out_proj GEMM.
#define HS_STRIDE 20   // floats; 80B: 16B-aligned, breaks 64B bank pattern
__global__ void scan_phaseC(const _Float16* __restrict__ dlth,
                            const _Float16* __restrict__ xsch,
                            const float* __restrict__ bc,
                            const _Float16* __restrict__ xzh,
                            const float* __restrict__ A_log,
                            const float* __restrict__ Dv,
                            const float* __restrict__ hin,
                            float* __restrict__ hidden,
                            _Float16* __restrict__ yh) {
  __shared__ float hs[2][256 * HS_STRIDE];
  int tid = threadIdx.x;
  int d0 = blockIdx.x * 256;
  int d = d0 + tid;
  int c = blockIdx.y;
  int b = blockIdx.z;
  float Av[DS];
#pragma unroll
  for (int n = 0; n < DS; n += 4) {
    float4 v = *(const float4*)(A_log + d * DS + n);
    Av[n] = -__expf(v.x); Av[n+1] = -__expf(v.y);
    Av[n+2] = -__expf(v.z); Av[n+3] = -__expf(v.w);
  }
  float Dd = Dv[d];
  float h[DS];
  size_t so = ((size_t)(b * NC + c) * DI + d) * DS;
#pragma unroll
  for (int n = 0; n < DS; n += 4) {
    float4 v = *(const float4*)(hin + so + n);
    h[n] = v.x; h[n+1] = v.y; h[n+2] = v.z; h[n+3] = v.w;
  }
  size_t row = (size_t)b * LSEQ + (size_t)c * CLEN;
  for (int t = 0; t < CLEN; ++t, ++row) {
    int bufi = t & 1;
    float dlt = (float)dlth[row * DI + d];
    float xv  = (float)xsch[row * DI + d];
    float dx = dlt * xv;
    float y = 0.f;
#pragma unroll
    for (int n = 0; n < DS; ++n) {
      float Bn = bc[row * 32 + n];
      float Cn = bc[row * 32 + 16 + n];
      float dA = __expf(dlt * Av[n]);
      h[n] = dA * h[n] + dx * Bn;
      y += h[n] * Cn;
    }
    // stage h into LDS, then cooperatively write 16KB contiguous (nontemporal)
#pragma unroll
    for (int n = 0; n < DS; n += 4)
      *(f32x4*)&hs[bufi][tid * HS_STRIDE + n] = (f32x4){h[n], h[n+1], h[n+2], h[n+3]};
    __syncthreads();
    size_t basef = ((size_t)row * DI + d0) * DS;   // 4096 floats for this block
#pragma unroll
    for (int k = 0; k < 4; ++k) {
      int f4 = tid + 256 * k;            // float4 index within slab
      int owner = f4 >> 2;
      int elem = (f4 & 3) * 4;
      f32x4 v = *(const f32x4*)&hs[bufi][owner * HS_STRIDE + elem];
      __builtin_nontemporal_store(v, (f32x4*)&hidden[basef + (size_t)f4 * 4]);
    }
    float zv = (float)xzh[row * (2 * DI) + DI + d];
    float sz = zv / (1.f + __expf(-zv));
    yh[row * DI + d] = (_Float16)((y + xv * Dd) * sz);
  }
}

extern "C" void kernel_launch(void* const* d_in, const int* in_sizes, int n_in,
                              void* d_out, int out_size, void* d_ws, size_t ws_size,
                              hipStream_t stream) {
  const float* x         = (const float*)d_in[0];
  const float* in_proj_w = (const float*)d_in[1];
  const float* conv_w    = (const float*)d_in[2];
  const float* conv_b    = (const float*)d_in[3];
  const float* x_proj_w  = (const float*)d_in[4];
  const float* dt_proj_w = (const float*)d_in[5];
  const float* dt_proj_b = (const float*)d_in[6];
  const float* out_proj_w= (const float*)d_in[7];
  const float* A_log     = (const float*)d_in[8];
  const float* Dvec      = (const float*)d_in[9];

  float* out    = (float*)d_out;                            // (B,L,DM)
  float* hidden = (float*)d_out + (size_t)BSZ * LSEQ * DM;  // (B,L,DI,DS)

  float* ws  = (float*)d_ws;
  float* bcbuf = ws;                                   // (M, 32)
  float* hloc  = bcbuf + (size_t)MROWS * 32;           // (B,NC,DI,DS) 4M
  float* hin   = hloc + (size_t)BSZ * NC * DI * DS;    // (B,NC,DI,DS) 4M
  float* dsum  = hin  + (size_t)BSZ * NC * DI * DS;    // (B,NC,DI)  256K
  float* outP  = dsum + (size_t)BSZ * NC * DI;         // 2x(M,DM)   4M

  _Float16* hp = (_Float16*)(outP + (size_t)2 * MROWS * DM);
  _Float16* xh   = hp;                                 // (M,DM)     2M
  _Float16* wih  = xh + (size_t)MROWS * DM;            // (2DI,DM)   4M
  _Float16* dtwp = wih + (size_t)2 * DI * DM;          // (NDT,DI)   4.45M
  _Float16* oh   = dtwp + (size_t)NDT * DI;            // (DM,DI)    2M
  _Float16* xzh  = oh + (size_t)DM * DI;               // (M,2DI)    8M
  _Float16* dlth = xzh + (size_t)MROWS * 2 * DI;       // (M,DI)     4M
  _Float16* xsch = dlth + (size_t)MROWS * DI;          // (M,DI)     4M
  _Float16* yh   = xsch + (size_t)MROWS * DI;          // (M,DI)     4M

  dim3 blk(256);

  // 0) merged prep: cvt x + all weight matrices to fp16 (+ dt/bc fusion pad)
  prep<<<dim3(6272), blk, 0, stream>>>(x, in_proj_w, dt_proj_w, x_proj_w,
                                       out_proj_w, xh, wih, dtwp, oh);

  // 1) xz = x @ in_proj_w^T -> fp16  (M=2048, N=4096, K=1024); 512 blocks
  gemm_mfma<128, 128, 1><<<dim3((2 * DI) / 128, MROWS / 128), blk, 0, stream>>>(
      xh, wih, nullptr, xzh, nullptr, MROWS, 2 * DI, DM, 2 * DI);

  // 2) depthwise conv + silu -> xsch (fp16, vectorized 8/thread)
  conv_silu<<<dim3((BSZ * LSEQ * DI / 8) / 256), blk, 0, stream>>>(
      xzh, conv_w, conv_b, xsch);

  // 3) fused dt+bc GEMM (TM=64: 544 blocks, balanced at 3/CU LDS cap)
  gemm_mfma<64, 128, 3><<<dim3(NDT / 128, MROWS / 64), blk, 0, stream>>>(
      xsch, dtwp, dt_proj_b, dlth, bcbuf, MROWS, NDT, DI, DI);

  // 4) chunked parallel scan -> hidden, y (fp16)
  scan_phaseA<<<dim3(DI / 256, NC, BSZ), blk, 0, stream>>>(
      dlth, xsch, bcbuf, A_log, hloc, dsum);
  scan_phaseB<<<dim3((BSZ * DI) / 4), blk, 0, stream>>>(
      hloc, dsum, A_log, hin);
  scan_phaseC<<<dim3(DI / 256, NC, BSZ), blk, 0, stream>>>(
      dlth, xsch, bcbuf, xzh, A_log, Dvec, hin, hidden, yh);

  // 5) out partials (split-K=2; 512 blocks at 2/CU), then out = P0+P1
  gemm_mfma<64, 128, 0><<<dim3(DM / 128, MROWS / 64, 2), blk, 0, stream>>>(
      yh, oh, nullptr, outP, nullptr, MROWS, DM, DI, DM);
  reduce2<<<dim3((MROWS * DM) / 1024), blk, 0, stream>>>(
      outP, out, MROWS * DM);
}